// Round 1
// baseline (558.958 us; speedup 1.0000x reference)
//
#include <hip/hip_runtime.h>
#include <stdint.h>

#define NROW 8192
#define IN_F 512
#define OUT_F 64
#define ALPHA 0.2f

// Static device scratch (d_ws not needed; everything fully rewritten each call).
__device__ float g_wa1[IN_F];
__device__ float g_wa2[IN_F];
__device__ float g_f1[NROW];
__device__ float g_f2[NROW];
__device__ float g_zinv[NROW];
__device__ double g_colsum[NROW];
__device__ unsigned long long g_mask[(size_t)NROW * 128]; // 8 MB bit-mask, interleaved format

// Kernel A0: wa1 = W@a1, wa2 = W@a2 (fp64 accum), and zero the column sums.
__global__ void prep_wa(const float* __restrict__ W, const float* __restrict__ a) {
    int k = threadIdx.x;
    if (k < IN_F) {
        double s1 = 0.0, s2 = 0.0;
        for (int t = 0; t < OUT_F; ++t) {
            double w = (double)W[k * OUT_F + t];
            s1 += w * (double)a[t];
            s2 += w * (double)a[OUT_F + t];
        }
        g_wa1[k] = (float)s1;
        g_wa2[k] = (float)s2;
        #pragma unroll
        for (int i = 0; i < 16; ++i) g_colsum[k * 16 + i] = 0.0;
    }
}

// Kernel A1: f1[i] = input[i,:]@wa1, f2[i] = input[i,:]@wa2. One wave per row.
__global__ void __launch_bounds__(256) compute_f(const float* __restrict__ in) {
    int wave = threadIdx.x >> 6, lane = threadIdx.x & 63;
    int row = blockIdx.x * 4 + wave;
    const float4* in4  = (const float4*)(in + (size_t)row * IN_F);
    const float4* wa14 = (const float4*)g_wa1;
    const float4* wa24 = (const float4*)g_wa2;
    double s1 = 0.0, s2 = 0.0;
    #pragma unroll
    for (int half = 0; half < 2; ++half) {
        int idx = half * 64 + lane;
        float4 x = in4[idx];
        float4 u = wa14[idx];
        float4 v = wa24[idx];
        s1 += (double)x.x*u.x + (double)x.y*u.y + (double)x.z*u.z + (double)x.w*u.w;
        s2 += (double)x.x*v.x + (double)x.y*v.y + (double)x.z*v.z + (double)x.w*v.w;
    }
    #pragma unroll
    for (int off = 32; off > 0; off >>= 1) {
        s1 += __shfl_down(s1, off, 64);
        s2 += __shfl_down(s2, off, 64);
    }
    if (lane == 0) { g_f1[row] = (float)s1; g_f2[row] = (float)s2; }
}

// Kernel B: the single pass over adj (268 MB). Per row: Z[i] (no max-subtraction
// needed, |e|<=~30) and the adjacency bitmask (interleaved: word g*4+c, bit l
// covers column 256*g + 4*l + c — matches the int4+ballot access pattern).
__global__ void __launch_bounds__(256) row_z_mask(const int* __restrict__ adj) {
    __shared__ float f2s[NROW];
    __shared__ double zpart[16];
    int tid = threadIdx.x;
    int wave = tid >> 6, lane = tid & 63;
    for (int k = tid; k < NROW / 4; k += 256)
        ((float4*)f2s)[k] = ((const float4*)g_f2)[k];
    __syncthreads();
    int row0 = blockIdx.x * 4;
    for (int r = 0; r < 4; ++r) {
        int row = row0 + r;
        float f1r = g_f1[row];
        const int4* arow = (const int4*)(adj + (size_t)row * NROW) + wave * 512;
        unsigned long long myword = 0;
        double zacc = 0.0;
        #pragma unroll
        for (int it = 0; it < 8; ++it) {
            int4 av = arow[it * 64 + lane];
            int colbase = wave * 2048 + it * 256 + lane * 4;
            float4 f2v = *(const float4*)&f2s[colbase];
            bool p0 = av.x > 0, p1 = av.y > 0, p2 = av.z > 0, p3 = av.w > 0;
            unsigned long long b0 = __ballot(p0), b1 = __ballot(p1);
            unsigned long long b2 = __ballot(p2), b3 = __ballot(p3);
            int bl = it * 4;
            if (lane == bl)     myword = b0;
            if (lane == bl + 1) myword = b1;
            if (lane == bl + 2) myword = b2;
            if (lane == bl + 3) myword = b3;
            float e0 = f1r + f2v.x; e0 = e0 > 0.f ? e0 : ALPHA * e0;
            float e1 = f1r + f2v.y; e1 = e1 > 0.f ? e1 : ALPHA * e1;
            float e2 = f1r + f2v.z; e2 = e2 > 0.f ? e2 : ALPHA * e2;
            float e3 = f1r + f2v.w; e3 = e3 > 0.f ? e3 : ALPHA * e3;
            zacc += p0 ? (double)expf(e0) : 0.0;
            zacc += p1 ? (double)expf(e1) : 0.0;
            zacc += p2 ? (double)expf(e2) : 0.0;
            zacc += p3 ? (double)expf(e3) : 0.0;
        }
        if (lane < 32) g_mask[(size_t)row * 128 + wave * 32 + lane] = myword;
        #pragma unroll
        for (int off = 32; off > 0; off >>= 1) zacc += __shfl_down(zacc, off, 64);
        if (lane == 0) zpart[r * 4 + wave] = zacc;
    }
    __syncthreads();
    if (tid < 4) {
        double z = zpart[tid*4+0] + zpart[tid*4+1] + zpart[tid*4+2] + zpart[tid*4+3];
        g_zinv[row0 + tid] = (float)(1.0 / z);
    }
}

// Kernel C: sig_scores[j] = sum_i bit(i,j) * expf(LR(f1[i]+f2[j])) * zinv[i].
// Thread <-> column; 256-row chunk per block; fp64 register accum; f64 atomic.
__global__ void __launch_bounds__(256) colsum_kernel() {
    int tid = threadIdx.x;
    int cb = blockIdx.x & 31;
    int rb = blockIdx.x >> 5;
    int j = cb * 256 + tid;
    float f2j = g_f2[j];
    int wsel = cb * 4 + (tid & 3);
    int bit = (tid >> 2) & 63;
    double acc = 0.0;
    int i0 = rb * 256;
    for (int i = i0; i < i0 + 256; ++i) {
        unsigned long long wv = g_mask[(size_t)i * 128 + wsel];
        float e = g_f1[i] + f2j;
        e = e > 0.f ? e : ALPHA * e;
        float val = expf(e) * g_zinv[i];
        acc += ((wv >> bit) & 1ULL) ? (double)val : 0.0;
    }
    atomicAdd(&g_colsum[j], acc);
}

// Kernel D: exact top-K with lax.top_k tie semantics.
// key = (monotonic_f32_bits << 13) | (8191 - idx); radix-select the K-th
// largest key (6 x 8-bit levels), collect the K keys >= threshold, bitonic
// sort 1024 descending, emit indices.
__global__ void __launch_bounds__(1024) topk_kernel(int* __restrict__ out, int K) {
    __shared__ unsigned int sbits[NROW];          // 32 KB
    __shared__ unsigned int hist[256];
    __shared__ unsigned long long cand[1024];
    __shared__ unsigned long long s_prefix;
    __shared__ unsigned int s_want, s_cnt;
    int tid = threadIdx.x;
    for (int k = tid; k < NROW; k += 1024) {
        float s = (float)g_colsum[k];
        unsigned int u = __float_as_uint(s);
        u = (u & 0x80000000u) ? ~u : (u | 0x80000000u); // monotonic transform
        sbits[k] = u;
    }
    if (tid == 0) { s_prefix = 0ULL; s_want = (unsigned)K; s_cnt = 0; }
    __syncthreads();
    for (int lvl = 0; lvl < 6; ++lvl) {
        int shift = 40 - lvl * 8;
        if (tid < 256) hist[tid] = 0;
        __syncthreads();
        unsigned long long pmask = (lvl == 0) ? 0ULL : (~0ULL << (shift + 8));
        unsigned long long prefix = s_prefix;
        for (int k = tid; k < NROW; k += 1024) {
            unsigned long long kk =
                ((unsigned long long)sbits[k] << 13) | (unsigned long long)(8191 - k);
            if ((kk & pmask) == prefix)
                atomicAdd(&hist[(unsigned)(kk >> shift) & 255u], 1u);
        }
        __syncthreads();
        if (tid == 0) {
            unsigned cum = 0; int b = 255;
            for (; b >= 0; --b) { cum += hist[b]; if (cum >= s_want) break; }
            if (b < 0) b = 0;
            s_want -= (cum - hist[b]);
            s_prefix |= ((unsigned long long)b << shift);
        }
        __syncthreads();
    }
    unsigned long long thr = s_prefix; // exact K-th largest key (keys are unique)
    for (int k = tid; k < NROW; k += 1024) {
        unsigned long long kk =
            ((unsigned long long)sbits[k] << 13) | (unsigned long long)(8191 - k);
        if (kk >= thr) {
            unsigned pos = atomicAdd(&s_cnt, 1u);
            if (pos < 1024u) cand[pos] = kk;
        }
    }
    __syncthreads();
    unsigned cnt = s_cnt;
    if ((unsigned)tid >= cnt) cand[tid] = 0ULL;
    __syncthreads();
    for (int k2 = 2; k2 <= 1024; k2 <<= 1) {
        for (int jj = k2 >> 1; jj > 0; jj >>= 1) {
            int ixj = tid ^ jj;
            if (ixj > tid) {
                unsigned long long a = cand[tid], b = cand[ixj];
                bool up = ((tid & k2) == 0);
                if (up ? (a < b) : (a > b)) { cand[tid] = b; cand[ixj] = a; }
            }
            __syncthreads();
        }
    }
    if (tid < K) out[tid] = 8191 - (int)(cand[tid] & 0x1FFFULL);
}

extern "C" void kernel_launch(void* const* d_in, const int* in_sizes, int n_in,
                              void* d_out, int out_size, void* d_ws, size_t ws_size,
                              hipStream_t stream) {
    const float* input = (const float*)d_in[0];
    const int*   adj   = (const int*)d_in[1];
    const float* W     = (const float*)d_in[2];
    const float* a     = (const float*)d_in[3];
    int* out = (int*)d_out;
    int K = out_size; // 512

    prep_wa<<<1, 512, 0, stream>>>(W, a);
    compute_f<<<NROW / 4, 256, 0, stream>>>(input);
    row_z_mask<<<NROW / 4, 256, 0, stream>>>(adj);
    colsum_kernel<<<1024, 256, 0, stream>>>();
    topk_kernel<<<1, 1024, 0, stream>>>(out, K);
}

// Round 2
// 513.441 us; speedup vs baseline: 1.0887x; 1.0887x over previous
//
#include <hip/hip_runtime.h>
#include <stdint.h>

#define NROW 8192
#define IN_F 512
#define OUT_F 64
#define ALPHA 0.2f

// Static device scratch (fully rewritten every call).
__device__ float  g_wa1[IN_F];
__device__ float  g_wa2[IN_F];
__device__ float  g_f1[NROW];
__device__ float  g_f2[NROW];
__device__ float  g_E2f[NROW];   // (float)exp(f2)
__device__ float  g_F2f[NROW];   // (float)exp(0.2*f2)
__device__ double g_E2d[NROW];   // exp(f2)
__device__ double g_F2d[NROW];   // exp(0.2*f2)
__device__ double g_accp[NROW];  // sum over adj&pos of exp(f2[j])
__device__ double g_accn[NROW];  // sum over adj&neg of exp(0.2*f2[j])
__device__ double g_G1[NROW];    // exp(f1)/Z
__device__ double g_H1[NROW];    // exp(0.2*f1)/Z
__device__ double g_colsum[NROW];
__device__ unsigned long long g_mask[(size_t)NROW * 128]; // 8 MB bitmask

// A0: wa1 = W@a1, wa2 = W@a2 (fp64 accum); zero column sums.
__global__ void prep_wa(const float* __restrict__ W, const float* __restrict__ a) {
    int k = threadIdx.x;
    if (k < IN_F) {
        double s1 = 0.0, s2 = 0.0;
        for (int t = 0; t < OUT_F; ++t) {
            double w = (double)W[k * OUT_F + t];
            s1 += w * (double)a[t];
            s2 += w * (double)a[OUT_F + t];
        }
        g_wa1[k] = (float)s1;
        g_wa2[k] = (float)s2;
        #pragma unroll
        for (int i = 0; i < 16; ++i) g_colsum[k * 16 + i] = 0.0;
    }
}

// A1: f1/f2 per row (fp64 accum) + the four exp tables (from the f32-rounded
// f1/f2, matching the reference's quantization points). One wave per row.
__global__ void __launch_bounds__(256) compute_f(const float* __restrict__ in) {
    int wave = threadIdx.x >> 6, lane = threadIdx.x & 63;
    int row = blockIdx.x * 4 + wave;
    const float4* in4  = (const float4*)(in + (size_t)row * IN_F);
    const float4* wa14 = (const float4*)g_wa1;
    const float4* wa24 = (const float4*)g_wa2;
    double s1 = 0.0, s2 = 0.0;
    #pragma unroll
    for (int half = 0; half < 2; ++half) {
        int idx = half * 64 + lane;
        float4 x = in4[idx];
        float4 u = wa14[idx];
        float4 v = wa24[idx];
        s1 += (double)x.x*u.x + (double)x.y*u.y + (double)x.z*u.z + (double)x.w*u.w;
        s2 += (double)x.x*v.x + (double)x.y*v.y + (double)x.z*v.z + (double)x.w*v.w;
    }
    #pragma unroll
    for (int off = 32; off > 0; off >>= 1) {
        s1 += __shfl_down(s1, off, 64);
        s2 += __shfl_down(s2, off, 64);
    }
    if (lane == 0) {
        float f1 = (float)s1, f2 = (float)s2;
        g_f1[row] = f1; g_f2[row] = f2;
        double e2 = exp((double)f2), g2 = exp(0.2 * (double)f2);
        g_E2d[row] = e2;        g_F2d[row] = g2;
        g_E2f[row] = (float)e2; g_F2f[row] = (float)g2;
    }
}

// B: the single 268 MB pass over adj. Per row i accumulates
//   accp = sum_{adj, f1+f2>0} exp(f2[j]),  accn = sum_{adj, else} exp(0.2 f2[j])
// (so Z = exp(f1)*accp + exp(0.2 f1)*accn), and packs adj into the bitmask.
// No expf in the inner loop — sign test via monotone F2[j] > exp(-0.2 f1).
__global__ void __launch_bounds__(256) row_z_mask(const int* __restrict__ adj) {
    __shared__ float E2s[NROW];   // 32 KB
    __shared__ float F2s[NROW];   // 32 KB
    __shared__ double zp[16], zn[16];
    int tid = threadIdx.x;
    int wave = tid >> 6, lane = tid & 63;
    for (int k = tid; k < NROW / 4; k += 256) {
        ((float4*)E2s)[k] = ((const float4*)g_E2f)[k];
        ((float4*)F2s)[k] = ((const float4*)g_F2f)[k];
    }
    __syncthreads();
    int row0 = blockIdx.x * 4;
    for (int r = 0; r < 4; ++r) {
        int row = row0 + r;
        float f1r = g_f1[row];
        float Ft = expf(-0.2f * f1r);   // pos  <=>  F2[j] > Ft
        const int4* arow = (const int4*)(adj + (size_t)row * NROW) + wave * 512;
        unsigned long long myword = 0;
        double accp = 0.0, accn = 0.0;
        #pragma unroll
        for (int it = 0; it < 8; ++it) {
            int4 av = arow[it * 64 + lane];
            int colbase = wave * 2048 + it * 256 + lane * 4;
            float4 E2v = *(const float4*)&E2s[colbase];
            float4 F2v = *(const float4*)&F2s[colbase];
            bool p0 = av.x > 0, p1 = av.y > 0, p2 = av.z > 0, p3 = av.w > 0;
            unsigned long long b0 = __ballot(p0), b1 = __ballot(p1);
            unsigned long long b2 = __ballot(p2), b3 = __ballot(p3);
            int bl = it * 4;
            if (lane == bl)     myword = b0;
            if (lane == bl + 1) myword = b1;
            if (lane == bl + 2) myword = b2;
            if (lane == bl + 3) myword = b3;
            bool q0 = F2v.x > Ft, q1 = F2v.y > Ft, q2 = F2v.z > Ft, q3 = F2v.w > Ft;
            accp += (p0 && q0) ? (double)E2v.x : 0.0;
            accn += (p0 && !q0) ? (double)F2v.x : 0.0;
            accp += (p1 && q1) ? (double)E2v.y : 0.0;
            accn += (p1 && !q1) ? (double)F2v.y : 0.0;
            accp += (p2 && q2) ? (double)E2v.z : 0.0;
            accn += (p2 && !q2) ? (double)F2v.z : 0.0;
            accp += (p3 && q3) ? (double)E2v.w : 0.0;
            accn += (p3 && !q3) ? (double)F2v.w : 0.0;
        }
        if (lane < 32) g_mask[(size_t)row * 128 + wave * 32 + lane] = myword;
        #pragma unroll
        for (int off = 32; off > 0; off >>= 1) {
            accp += __shfl_down(accp, off, 64);
            accn += __shfl_down(accn, off, 64);
        }
        if (lane == 0) { zp[r * 4 + wave] = accp; zn[r * 4 + wave] = accn; }
    }
    __syncthreads();
    if (tid < 4) {
        g_accp[row0 + tid] = zp[tid*4+0] + zp[tid*4+1] + zp[tid*4+2] + zp[tid*4+3];
        g_accn[row0 + tid] = zn[tid*4+0] + zn[tid*4+1] + zn[tid*4+2] + zn[tid*4+3];
    }
}

// B2: per-row softmax-normalized factor tables G1 = exp(f1)/Z, H1 = exp(0.2 f1)/Z.
__global__ void __launch_bounds__(256) prep_gh() {
    int i = blockIdx.x * 256 + threadIdx.x;
    double f1d = (double)g_f1[i];
    double e1 = exp(f1d), h1 = exp(0.2 * f1d);
    double Z = e1 * g_accp[i] + h1 * g_accn[i];
    double zinv = 1.0 / Z;
    g_G1[i] = e1 * zinv;
    g_H1[i] = h1 * zinv;
}

// C: sig_scores[j] += E2d[j]*sum_{i: adj,pos} G1[i] + F2d[j]*sum_{i: adj,neg} H1[i]
// over a 256-row chunk per block. No exp in the loop; fp32 sign matches ref.
__global__ void __launch_bounds__(256) colsum_kernel() {
    __shared__ float  f1s[256];
    __shared__ double G1s[256], H1s[256];
    __shared__ unsigned long long msk[1024];   // this cb's 4 words x 256 rows
    int tid = threadIdx.x;
    int cb = blockIdx.x & 31;
    int rb = blockIdx.x >> 5;
    int j = cb * 256 + tid;
    float f2j = g_f2[j];
    int i0 = rb * 256;
    f1s[tid] = g_f1[i0 + tid];
    G1s[tid] = g_G1[i0 + tid];
    H1s[tid] = g_H1[i0 + tid];
    for (int t = tid; t < 1024; t += 256)
        msk[t] = g_mask[(size_t)(i0 + (t >> 2)) * 128 + cb * 4 + (t & 3)];
    __syncthreads();
    int c = tid & 3, bit = (tid >> 2) & 63;
    double accp = 0.0, accn = 0.0;
    for (int i = 0; i < 256; ++i) {
        unsigned long long wv = msk[i * 4 + c];
        bool b = (wv >> bit) & 1ULL;
        float e = f1s[i] + f2j;
        bool pos = e > 0.0f;
        accp += (b && pos)  ? G1s[i] : 0.0;
        accn += (b && !pos) ? H1s[i] : 0.0;
    }
    double res = g_E2d[j] * accp + g_F2d[j] * accn;
    atomicAdd(&g_colsum[j], res);
}

// D: exact top-K, lax.top_k tie semantics (unchanged from passing version).
__global__ void __launch_bounds__(1024) topk_kernel(int* __restrict__ out, int K) {
    __shared__ unsigned int sbits[NROW];
    __shared__ unsigned int hist[256];
    __shared__ unsigned long long cand[1024];
    __shared__ unsigned long long s_prefix;
    __shared__ unsigned int s_want, s_cnt;
    int tid = threadIdx.x;
    for (int k = tid; k < NROW; k += 1024) {
        float s = (float)g_colsum[k];
        unsigned int u = __float_as_uint(s);
        u = (u & 0x80000000u) ? ~u : (u | 0x80000000u);
        sbits[k] = u;
    }
    if (tid == 0) { s_prefix = 0ULL; s_want = (unsigned)K; s_cnt = 0; }
    __syncthreads();
    for (int lvl = 0; lvl < 6; ++lvl) {
        int shift = 40 - lvl * 8;
        if (tid < 256) hist[tid] = 0;
        __syncthreads();
        unsigned long long pmask = (lvl == 0) ? 0ULL : (~0ULL << (shift + 8));
        unsigned long long prefix = s_prefix;
        for (int k = tid; k < NROW; k += 1024) {
            unsigned long long kk =
                ((unsigned long long)sbits[k] << 13) | (unsigned long long)(8191 - k);
            if ((kk & pmask) == prefix)
                atomicAdd(&hist[(unsigned)(kk >> shift) & 255u], 1u);
        }
        __syncthreads();
        if (tid == 0) {
            unsigned cum = 0; int b = 255;
            for (; b >= 0; --b) { cum += hist[b]; if (cum >= s_want) break; }
            if (b < 0) b = 0;
            s_want -= (cum - hist[b]);
            s_prefix |= ((unsigned long long)b << shift);
        }
        __syncthreads();
    }
    unsigned long long thr = s_prefix;
    for (int k = tid; k < NROW; k += 1024) {
        unsigned long long kk =
            ((unsigned long long)sbits[k] << 13) | (unsigned long long)(8191 - k);
        if (kk >= thr) {
            unsigned pos = atomicAdd(&s_cnt, 1u);
            if (pos < 1024u) cand[pos] = kk;
        }
    }
    __syncthreads();
    unsigned cnt = s_cnt;
    if ((unsigned)tid >= cnt) cand[tid] = 0ULL;
    __syncthreads();
    for (int k2 = 2; k2 <= 1024; k2 <<= 1) {
        for (int jj = k2 >> 1; jj > 0; jj >>= 1) {
            int ixj = tid ^ jj;
            if (ixj > tid) {
                unsigned long long a = cand[tid], b = cand[ixj];
                bool up = ((tid & k2) == 0);
                if (up ? (a < b) : (a > b)) { cand[tid] = b; cand[ixj] = a; }
            }
            __syncthreads();
        }
    }
    if (tid < K) out[tid] = 8191 - (int)(cand[tid] & 0x1FFFULL);
}

extern "C" void kernel_launch(void* const* d_in, const int* in_sizes, int n_in,
                              void* d_out, int out_size, void* d_ws, size_t ws_size,
                              hipStream_t stream) {
    const float* input = (const float*)d_in[0];
    const int*   adj   = (const int*)d_in[1];
    const float* W     = (const float*)d_in[2];
    const float* a     = (const float*)d_in[3];
    int* out = (int*)d_out;
    int K = out_size; // 512

    prep_wa<<<1, 512, 0, stream>>>(W, a);
    compute_f<<<NROW / 4, 256, 0, stream>>>(input);
    row_z_mask<<<NROW / 4, 256, 0, stream>>>(adj);
    prep_gh<<<NROW / 256, 256, 0, stream>>>();
    colsum_kernel<<<1024, 256, 0, stream>>>();
    topk_kernel<<<1, 1024, 0, stream>>>(out, K);
}